// Round 1
// baseline (46.547 us; speedup 1.0000x reference)
//
#include <hip/hip_runtime.h>
#include <math.h>

#define N_I 1152
#define N_O 10
#define N_D 16
#define BLK 256
#define KST 18   // (1152*16 floats) / 4 / 256 threads

// One block per (b, o) output capsule. u-slice (1152 x 16 fp32 = 72 KB) staged
// in LDS once via global_load_lds; all 3 routing iterations run from LDS.
// Thread layout for compute: d4 = tid&3 (owns dims 4*d4..4*d4+3),
// ig = tid>>2 (i-capsules i == ig mod 64). float4 LDS reads are
// conflict-free (8 accesses/bank per wave instruction).
__global__ __launch_bounds__(BLK, 2)
void caps_route(const float* __restrict__ u_hat, float* __restrict__ out)
{
    __shared__ float4 u4[N_I * 4];                  // u[i][d], 72 KB, linear
    __shared__ float  scr_s[4][16];                 // per-wave partial s
    __shared__ float  scr_e[4];                     // per-wave partial exp-sum
    __shared__ __align__(16) float vcum[16];        // cumulative v (= logits state)

    const int tid  = threadIdx.x;
    const int wave = tid >> 6;
    const int lane = tid & 63;
    const int d4   = tid & 3;
    const int ig   = tid >> 2;

    // XCD-aware swizzle: consecutive work-ids (same b, o=0..9) land on one XCD
    // so the 640B-contiguous (b,i) rows get L2 reuse across the 10 o-blocks.
    const int bid = blockIdx.x;
    const int nwg = gridDim.x;
    int wid = bid;
    if ((nwg & 7) == 0) wid = (bid & 7) * (nwg >> 3) + (bid >> 3);
    const int b = wid / N_O;
    const int o = wid - b * N_O;

    const float* gbase = u_hat + (size_t)b * (N_I * N_O * N_D) + (size_t)o * N_D;

    // ---- global -> LDS, direct 16 B/lane (linear LDS dest, per-lane global src) ----
    {
        float* lds_f = (float*)u4;
        #pragma unroll
        for (int j = 0; j < KST; ++j) {
            const int f   = j * BLK + tid;     // float4 slot
            const int row = f >> 2;
            const int ch  = f & 3;
            const float* g = gbase + row * (N_O * N_D) + ch * 4;
            float* dst = lds_f + (size_t)(j * BLK + (tid & ~63)) * 4; // wave-uniform base
            __builtin_amdgcn_global_load_lds(
                (const __attribute__((address_space(1))) void*)g,
                (__attribute__((address_space(3))) void*)dst,
                16, 0, 0);
        }
    }
    if (tid < 16) vcum[tid] = 0.0f;
    __syncthreads();

    float4 vc = make_float4(0.f, 0.f, 0.f, 0.f);

    for (int r = 0; r < 3; ++r) {
        float4 s4 = make_float4(0.f, 0.f, 0.f, 0.f);
        float esum = 0.0f;
        if (r == 0) {
            // b == 0 -> uniform weights; e_i = 1
            #pragma unroll
            for (int k = 0; k < KST; ++k) {
                const int i = ig + (k << 6);
                const float4 u = u4[(i << 2) | d4];
                s4.x += u.x; s4.y += u.y; s4.z += u.z; s4.w += u.w;
                esum += 1.0f;
            }
        } else {
            // fused: t_i = u_i . vcum ; e = exp(t_i); s += e*u ; esum += e
            #pragma unroll
            for (int k = 0; k < KST; ++k) {
                const int i = ig + (k << 6);
                const float4 u = u4[(i << 2) | d4];
                float p = u.x*vc.x + u.y*vc.y + u.z*vc.z + u.w*vc.w;
                p += __shfl_xor(p, 1);     // quad butterfly: full 16-dim dot
                p += __shfl_xor(p, 2);
                const float e = __expf(p);
                esum += e;
                s4.x += e*u.x; s4.y += e*u.y; s4.z += e*u.z; s4.w += e*u.w;
            }
        }
        // reduce over ig within the wave (tid bits 2..5)
        #pragma unroll
        for (int m = 4; m <= 32; m <<= 1) {
            s4.x += __shfl_xor(s4.x, m);
            s4.y += __shfl_xor(s4.y, m);
            s4.z += __shfl_xor(s4.z, m);
            s4.w += __shfl_xor(s4.w, m);
            esum += __shfl_xor(esum, m);
        }
        if (lane < 4) {
            scr_s[wave][lane*4+0] = s4.x;
            scr_s[wave][lane*4+1] = s4.y;
            scr_s[wave][lane*4+2] = s4.z;
            scr_s[wave][lane*4+3] = s4.w;
            if (lane == 0) scr_e[wave] = esum;
        }
        __syncthreads();
        if (tid < 16) {
            float s = 0.f, et = 0.f;
            #pragma unroll
            for (int w = 0; w < 4; ++w) { s += scr_s[w][tid]; et += scr_e[w]; }
            s /= et;                          // softmax normalization folded here
            float sq = s * s;
            sq += __shfl_xor(sq, 1);
            sq += __shfl_xor(sq, 2);
            sq += __shfl_xor(sq, 4);
            sq += __shfl_xor(sq, 8);
            const float nrm = sqrtf(sq);
            const float v = s * (nrm / (1.0f + sq));   // == sq*s/((1+sq)*nrm)
            if (r == 2) out[(size_t)wid * N_D + tid] = v;
            else        vcum[tid] += v;       // logits state: b_i = u_i . vcum
        }
        __syncthreads();
        if (r < 2) vc = ((const float4*)vcum)[d4];
    }
}

extern "C" void kernel_launch(void* const* d_in, const int* in_sizes, int n_in,
                              void* d_out, int out_size, void* d_ws, size_t ws_size,
                              hipStream_t stream)
{
    const float* u_hat = (const float*)d_in[0];
    float* out = (float*)d_out;
    const int B = in_sizes[0] / (N_I * N_O * N_D);
    hipLaunchKernelGGL(caps_route, dim3(B * N_O), dim3(BLK), 0, stream, u_hat, out);
}

// Round 2
// 37.031 us; speedup vs baseline: 1.2570x; 1.2570x over previous
//
#include <hip/hip_runtime.h>
#include <math.h>

#define N_I 1152
#define N_O 10
#define N_D 16
#define BLK 512
#define KPT 9   // i-rows per thread: 1152 / (BLK/4)

// One block per (b, o). Each thread holds its 9 x float4 slice of the
// 1152x16 u-tile in REGISTERS (36 VGPRs); all 3 routing iterations compute
// from registers. LDS is only ~0.6 KB of reduction scratch, so occupancy is
// VGPR-bound (~2-3 blocks/CU = 16-24 waves) instead of LDS-bound (was 8
// waves). Loads are plain global_load_dwordx4; latency hidden by TLP.
// Thread layout: d4 = tid&3 (dims 4*d4..4*d4+3), ig = tid>>2 (i = ig+128k).
__global__ __launch_bounds__(BLK, 4)
void caps_route(const float* __restrict__ u_hat, float* __restrict__ out)
{
    __shared__ float scr_s[8][16];                // per-wave partial s
    __shared__ float scr_e[8];                    // per-wave partial exp-sum
    __shared__ __align__(16) float vcum[16];      // cumulative v (= logit state)

    const int tid  = threadIdx.x;
    const int wave = tid >> 6;
    const int lane = tid & 63;
    const int d4   = tid & 3;
    const int ig   = tid >> 2;    // 0..127

    // XCD-aware swizzle: consecutive wids (same b, adjacent o) run adjacently
    // on one XCD, so the two o's sharing each 128B line hit L2.
    const int bid = blockIdx.x;
    const int nwg = gridDim.x;
    int wid = bid;
    if ((nwg & 7) == 0) wid = (bid & 7) * (nwg >> 3) + (bid >> 3);
    const int b = wid / N_O;
    const int o = wid - b * N_O;

    const float* gbase = u_hat + (size_t)b * (N_I * N_O * N_D)
                               + (size_t)o * N_D + d4 * 4;

    // ---- global -> registers: 9 x 16B per thread ----
    float4 u[KPT];
    #pragma unroll
    for (int k = 0; k < KPT; ++k) {
        const int i = ig + (k << 7);
        u[k] = *(const float4*)(gbase + (size_t)i * (N_O * N_D));
    }
    if (tid < 16) vcum[tid] = 0.0f;

    float4 vc = make_float4(0.f, 0.f, 0.f, 0.f);

    for (int r = 0; r < 3; ++r) {
        float4 s4 = make_float4(0.f, 0.f, 0.f, 0.f);
        float esum = 0.0f;
        if (r == 0) {
            // b == 0 -> uniform weights; e_i = 1
            #pragma unroll
            for (int k = 0; k < KPT; ++k) {
                s4.x += u[k].x; s4.y += u[k].y;
                s4.z += u[k].z; s4.w += u[k].w;
            }
            esum = (float)KPT;
        } else {
            // fused: t_i = u_i . vcum ; e = exp(t_i); s += e*u ; esum += e
            #pragma unroll
            for (int k = 0; k < KPT; ++k) {
                float p = u[k].x*vc.x + u[k].y*vc.y + u[k].z*vc.z + u[k].w*vc.w;
                p += __shfl_xor(p, 1);    // quad butterfly: full 16-dim dot
                p += __shfl_xor(p, 2);
                const float e = __expf(p);
                esum += e;
                s4.x += e*u[k].x; s4.y += e*u[k].y;
                s4.z += e*u[k].z; s4.w += e*u[k].w;
            }
        }
        // reduce over ig within the wave (lane bits 2..5)
        #pragma unroll
        for (int m = 4; m <= 32; m <<= 1) {
            s4.x += __shfl_xor(s4.x, m);
            s4.y += __shfl_xor(s4.y, m);
            s4.z += __shfl_xor(s4.z, m);
            s4.w += __shfl_xor(s4.w, m);
            esum += __shfl_xor(esum, m);
        }
        if (lane < 4) {
            scr_s[wave][lane*4+0] = s4.x;
            scr_s[wave][lane*4+1] = s4.y;
            scr_s[wave][lane*4+2] = s4.z;
            scr_s[wave][lane*4+3] = s4.w;
            if (lane == 0) scr_e[wave] = esum;
        }
        __syncthreads();
        if (tid < 16) {
            float s = 0.f, et = 0.f;
            #pragma unroll
            for (int w = 0; w < 8; ++w) { s += scr_s[w][tid]; et += scr_e[w]; }
            s /= et;                           // softmax normalization folded
            float sq = s * s;
            sq += __shfl_xor(sq, 1);
            sq += __shfl_xor(sq, 2);
            sq += __shfl_xor(sq, 4);
            sq += __shfl_xor(sq, 8);
            const float nrm = sqrtf(sq);
            const float v = s * (nrm / (1.0f + sq));   // == sq*s/((1+sq)*nrm)
            if (r == 2) out[(size_t)wid * N_D + tid] = v;
            else        vcum[tid] += v;        // logit state: b_i = u_i . vcum
        }
        __syncthreads();
        if (r < 2) vc = ((const float4*)vcum)[d4];
    }
}

extern "C" void kernel_launch(void* const* d_in, const int* in_sizes, int n_in,
                              void* d_out, int out_size, void* d_ws, size_t ws_size,
                              hipStream_t stream)
{
    const float* u_hat = (const float*)d_in[0];
    float* out = (float*)d_out;
    const int B = in_sizes[0] / (N_I * N_O * N_D);
    hipLaunchKernelGGL(caps_route, dim3(B * N_O), dim3(BLK), 0, stream, u_hat, out);
}